// Round 4
// baseline (62.062 us; speedup 1.0000x reference)
//
#include <hip/hip_runtime.h>

// ChamferLoss: preds (8,3,2048,8) f32, gts (8,3,2048) f32, idx (64,2) int.
// x[b][n][c] = preds[i0, c, n, m1]; y[b][n][c] = gts[i0, c, n]; i0=idx[b,0], m1=idx[b,1].
// loss = ( sum_j min_i ||x_i-y_j||^2 + sum_i min_j ||x_i-y_j||^2 ) / 64, summed over b.

#define NPTS 2048
#define NB 64
#define RCH 128                 // refs per chunk (halved -> 2048 blocks, 8/CU)
#define NRCH (NPTS / RCH)       // 16
#define QPT 8                   // queries per thread (256*8 == 2048)
#define BLK 256
#define NMIN (2 * NB * NPTS)    // 262144 min slots

#define PREDS_A 49152           // 3*2048*8
#define PREDS_C 16384           // 2048*8
#define GTS_A 6144              // 3*2048
#define GTS_C 2048

__global__ __launch_bounds__(256) void cf_init(unsigned* __restrict__ minbuf) {
    int i = blockIdx.x * 256 + threadIdx.x;
    minbuf[i] = 0x7F800000u;    // +inf
}

__global__ __launch_bounds__(BLK, 8) void cf_min(
    const float* __restrict__ preds, const float* __restrict__ gts,
    const int* __restrict__ idx, unsigned* __restrict__ minbuf)
{
    const int tid = threadIdx.x;
    const int bid = blockIdx.x;            // [dir:1][b:6][rchunk:4]
    const int rchunk = bid & (NRCH - 1);
    const int b = (bid >> 4) & 63;
    const int dir = bid >> 10;             // 0: queries=x refs=y ; 1: queries=y refs=x

    const int i0 = idx[2 * b];
    const int m1 = idx[2 * b + 1];

    const float* pbase = preds + i0 * PREDS_A + m1;  // x[c][n] at pbase[n*8 + c*PREDS_C]
    const float* gbase = gts + i0 * GTS_A;           // y[c][n] at gbase[n + c*GTS_C]

    // ---- stage this block's ref chunk into LDS as (r0,r1,r2, r0^2+r1^2+r2^2) ----
    __shared__ float4 sref[RCH];
    if (tid < RCH) {
        const int jj = rchunk * RCH + tid;
        float r0, r1, r2;
        if (dir == 0) {
            r0 = gbase[jj];
            r1 = gbase[jj + GTS_C];
            r2 = gbase[jj + 2 * GTS_C];
        } else {
            const float* pp = pbase + jj * 8;
            r0 = pp[0];
            r1 = pp[PREDS_C];
            r2 = pp[2 * PREDS_C];
        }
        const float rr = fmaf(r0, r0, fmaf(r1, r1, r2 * r2));
        sref[tid] = make_float4(r0, r1, r2, rr);
    }

    // ---- load this thread's 8 queries into registers (coords pre-scaled by -2) ----
    float nq0[QPT], nq1[QPT], nq2[QPT], rq[QPT], mn[QPT];
#pragma unroll
    for (int q = 0; q < QPT; ++q) {
        const int n = tid + BLK * q;
        float q0, q1, q2;
        if (dir == 0) {
            const float* pp = pbase + n * 8;
            q0 = pp[0]; q1 = pp[PREDS_C]; q2 = pp[2 * PREDS_C];
        } else {
            q0 = gbase[n]; q1 = gbase[n + GTS_C]; q2 = gbase[n + 2 * GTS_C];
        }
        rq[q]  = fmaf(q0, q0, fmaf(q1, q1, q2 * q2));
        nq0[q] = -2.0f * q0;
        nq1[q] = -2.0f * q1;
        nq2[q] = -2.0f * q2;
        mn[q]  = INFINITY;
    }

    __syncthreads();

    // ---- main loop: ref pairs; per pair-of-refs per query: 6 FMA + 1 min3 ----
#pragma unroll 2
    for (int j = 0; j < RCH; j += 2) {
        const float4 ra = sref[j];
        const float4 rb = sref[j + 1];
#pragma unroll
        for (int q = 0; q < QPT; ++q) {
            float ta = fmaf(nq0[q], ra.x, ra.w);
            ta = fmaf(nq1[q], ra.y, ta);
            ta = fmaf(nq2[q], ra.z, ta);
            float tb = fmaf(nq0[q], rb.x, rb.w);
            tb = fmaf(nq1[q], rb.y, tb);
            tb = fmaf(nq2[q], rb.z, tb);
            mn[q] = fminf(fminf(ta, tb), mn[q]);   // hope: v_min3_f32
        }
    }

    // ---- combine chunk partial mins: nonneg floats are uint-order-preserving ----
    unsigned* mb = minbuf + (dir * NB + b) * NPTS;
#pragma unroll
    for (int q = 0; q < QPT; ++q) {
        const int n = tid + BLK * q;
        const float d = fmaxf(rq[q] + mn[q], 0.0f);
        atomicMin(mb + n, __float_as_uint(d));
    }
}

__global__ __launch_bounds__(256) void cf_reduce1(const unsigned* __restrict__ minbuf,
                                                  float* __restrict__ partial) {
    __shared__ float sm[4];
    const int base = blockIdx.x * 1024;
    float s = 0.0f;
    for (int k = threadIdx.x; k < 1024; k += 256)
        s += __uint_as_float(minbuf[base + k]);
#pragma unroll
    for (int off = 32; off > 0; off >>= 1)
        s += __shfl_down(s, off, 64);
    if ((threadIdx.x & 63) == 0) sm[threadIdx.x >> 6] = s;
    __syncthreads();
    if (threadIdx.x == 0)
        partial[blockIdx.x] = sm[0] + sm[1] + sm[2] + sm[3];
}

__global__ __launch_bounds__(256) void cf_reduce2(const float* __restrict__ partial,
                                                  float* __restrict__ out) {
    __shared__ float sm[4];
    float s = partial[threadIdx.x];
#pragma unroll
    for (int off = 32; off > 0; off >>= 1)
        s += __shfl_down(s, off, 64);
    if ((threadIdx.x & 63) == 0) sm[threadIdx.x >> 6] = s;
    __syncthreads();
    if (threadIdx.x == 0)
        out[0] = (sm[0] + sm[1] + sm[2] + sm[3]) * (1.0f / 64.0f);
}

extern "C" void kernel_launch(void* const* d_in, const int* in_sizes, int n_in,
                              void* d_out, int out_size, void* d_ws, size_t ws_size,
                              hipStream_t stream) {
    const float* preds = (const float*)d_in[0];
    const float* gts   = (const float*)d_in[1];
    const int*   idx   = (const int*)d_in[2];
    float* out = (float*)d_out;

    unsigned* minbuf = (unsigned*)d_ws;                                   // 1 MiB
    float* partial   = (float*)((char*)d_ws + NMIN * sizeof(unsigned));   // 1 KiB

    cf_init<<<NMIN / 256, 256, 0, stream>>>(minbuf);
    cf_min<<<2 * NB * NRCH, BLK, 0, stream>>>(preds, gts, idx, minbuf);
    cf_reduce1<<<NMIN / 1024, 256, 0, stream>>>(minbuf, partial);
    cf_reduce2<<<1, 256, 0, stream>>>(partial, out);
}

// Round 5
// 51.162 us; speedup vs baseline: 1.2130x; 1.2130x over previous
//
#include <hip/hip_runtime.h>

// ChamferLoss: preds (8,3,2048,8) f32, gts (8,3,2048) f32, idx (64,2) int.
// x[b][n][c] = preds[i0, c, n, m1]; y[b][n][c] = gts[i0, c, n]; i0=idx[b,0], m1=idx[b,1].
// P[i][j] = |x_i|^2 + |y_j|^2 - 2 x_i.y_j ; loss = (sum_j min_i P + sum_i min_j P)/64.
// KEY: both loss terms come from the SAME P — compute each P-tile ONCE, reduce both axes.

#define NPTS 2048
#define NB 64
#define IT 128                  // i-rows per block
#define NIT (NPTS / IT)         // 16
#define JT 128                  // j-cols per inner tile
#define NJT (NPTS / JT)         // 16
#define BLK 256
#define NMIN (2 * NB * NPTS)    // 131072 row slots + 131072 col slots

#define PREDS_A 49152           // 3*2048*8
#define PREDS_C 16384           // 2048*8
#define GTS_A 6144              // 3*2048
#define GTS_C 2048

// padded LDS index: +1 float4 per 16 -> lane bank stride 2, max 2-way aliasing (free)
#define PADI(j) ((j) + ((j) >> 4))

static __device__ __forceinline__ float min3f(float a, float b, float c) {
    float d;
    asm("v_min3_f32 %0, %1, %2, %3" : "=v"(d) : "v"(a), "v"(b), "v"(c));
    return d;
}

__global__ __launch_bounds__(256) void cf_init(unsigned* __restrict__ minbuf) {
    int i = blockIdx.x * 256 + threadIdx.x;
    minbuf[i] = 0x7F800000u;    // +inf
}

__global__ void cf_tile(
    const float* __restrict__ preds, const float* __restrict__ gts,
    const int* __restrict__ idx, unsigned* __restrict__ minbuf)
{
    const int tid = threadIdx.x;
    const int bid = blockIdx.x;        // b*16 + it
    const int it = bid & 15;
    const int b = bid >> 4;

    const int i0 = idx[2 * b];
    const int m1 = idx[2 * b + 1];
    const float* pbase = preds + i0 * PREDS_A + m1;  // x[c][n] at pbase[n*8 + c*PREDS_C]
    const float* gbase = gts + i0 * GTS_A;           // y[c][n] at gbase[n + c*GTS_C]

    __shared__ float4 sq[PADI(IT - 1) + 1 + 1];      // queries (-2*q0,-2*q1,-2*q2, rq)
    __shared__ float4 sr[PADI(NPTS - 1) + 1 + 1];    // all refs (r0,r1,r2, rr)
    __shared__ float  scolw[4][JT];                  // per-wave col partials

    // ---- stage 128 queries (threads 0-127) ----
    if (tid < IT) {
        const int i = it * IT + tid;
        const float q0 = pbase[i * 8];
        const float q1 = pbase[i * 8 + PREDS_C];
        const float q2 = pbase[i * 8 + 2 * PREDS_C];
        const float rq = fmaf(q0, q0, fmaf(q1, q1, q2 * q2));
        sq[PADI(tid)] = make_float4(-2.f * q0, -2.f * q1, -2.f * q2, rq);
    }
    // ---- stage ALL 2048 refs (8 per thread, coalesced) ----
#pragma unroll
    for (int k = 0; k < 8; ++k) {
        const int j = tid + BLK * k;
        const float r0 = gbase[j];
        const float r1 = gbase[j + GTS_C];
        const float r2 = gbase[j + 2 * GTS_C];
        const float rr = fmaf(r0, r0, fmaf(r1, r1, r2 * r2));
        sr[PADI(j)] = make_float4(r0, r1, r2, rr);
    }
    __syncthreads();

    const int ty = tid >> 4, tx = tid & 15;

    // ---- per-thread query fragment (rows ty*8 .. ty*8+7) ----
    float nq0[8], nq1[8], nq2[8], rq[8], rmin[8];
#pragma unroll
    for (int u = 0; u < 8; ++u) {
        const float4 q = sq[PADI(ty * 8 + u)];
        nq0[u] = q.x; nq1[u] = q.y; nq2[u] = q.z; rq[u] = q.w;
        rmin[u] = INFINITY;
    }

    unsigned* rowbuf = minbuf;
    unsigned* colbuf = minbuf + NB * NPTS;

    for (int jt = 0; jt < NJT; ++jt) {
        // refs for this thread: cols jt*128 + tx*8 .. +7
        float4 r[8];
        const int rb = PADI(jt * JT + tx * 8);   // v<8 stays within one pad group
#pragma unroll
        for (int v = 0; v < 8; ++v) r[v] = sr[rb + v];

        float cmin[8];
#pragma unroll
        for (int v = 0; v < 8; ++v) cmin[v] = INFINITY;

        // ---- 8x8 register tile, 2x2 micro-tiles: 20 ops / 4 pairs ----
#pragma unroll
        for (int v = 0; v < 8; v += 2) {
#pragma unroll
            for (int u = 0; u < 8; u += 2) {
                float s00 = fmaf(nq2[u], r[v].z, r[v].w);
                s00 = fmaf(nq1[u], r[v].y, s00);
                s00 = fmaf(nq0[u], r[v].x, s00);
                float s01 = fmaf(nq2[u], r[v + 1].z, r[v + 1].w);
                s01 = fmaf(nq1[u], r[v + 1].y, s01);
                s01 = fmaf(nq0[u], r[v + 1].x, s01);
                float s10 = fmaf(nq2[u + 1], r[v].z, r[v].w);
                s10 = fmaf(nq1[u + 1], r[v].y, s10);
                s10 = fmaf(nq0[u + 1], r[v].x, s10);
                float s11 = fmaf(nq2[u + 1], r[v + 1].z, r[v + 1].w);
                s11 = fmaf(nq1[u + 1], r[v + 1].y, s11);
                s11 = fmaf(nq0[u + 1], r[v + 1].x, s11);
                // row mins accumulate s = rr_j - 2 x.y  (rq_i added at flush)
                rmin[u]     = min3f(s00, s01, rmin[u]);
                rmin[u + 1] = min3f(s10, s11, rmin[u + 1]);
                // col mins need full d = s + rq_i
                const float d00 = s00 + rq[u];
                const float d10 = s10 + rq[u + 1];
                const float d01 = s01 + rq[u];
                const float d11 = s11 + rq[u + 1];
                cmin[v]     = min3f(d00, d10, cmin[v]);
                cmin[v + 1] = min3f(d01, d11, cmin[v + 1]);
            }
        }

        // ---- col reduce: over 16 ty = 4 in-wave (xor 16,32) + 4 cross-wave via LDS ----
#pragma unroll
        for (int v = 0; v < 8; ++v) {
            float c = cmin[v];
            c = fminf(c, __shfl_xor(c, 16, 64));
            c = fminf(c, __shfl_xor(c, 32, 64));
            cmin[v] = c;
        }
        if (((tid >> 4) & 3) == 0) {                 // lanes 0-15 of each wave
            const int w = tid >> 6;
            *(float4*)&scolw[w][tx * 8]     = make_float4(cmin[0], cmin[1], cmin[2], cmin[3]);
            *(float4*)&scolw[w][tx * 8 + 4] = make_float4(cmin[4], cmin[5], cmin[6], cmin[7]);
        }
        __syncthreads();
        if (tid < JT) {
            float m = fminf(min3f(scolw[0][tid], scolw[1][tid], scolw[2][tid]), scolw[3][tid]);
            m = fmaxf(m, 0.0f);                      // nonneg -> uint order-preserving
            atomicMin(&colbuf[b * NPTS + jt * JT + tid], __float_as_uint(m));
        }
        __syncthreads();
    }

    // ---- row flush: reduce over 16 tx in-group, single exclusive writer ----
#pragma unroll
    for (int u = 0; u < 8; ++u) {
        float rm = rmin[u];
        rm = fminf(rm, __shfl_xor(rm, 1, 16));
        rm = fminf(rm, __shfl_xor(rm, 2, 16));
        rm = fminf(rm, __shfl_xor(rm, 4, 16));
        rm = fminf(rm, __shfl_xor(rm, 8, 16));
        rmin[u] = rm;
    }
    if (tx == 0) {
#pragma unroll
        for (int u = 0; u < 8; ++u) {
            const float d = fmaxf(rmin[u] + rq[u], 0.0f);
            rowbuf[b * NPTS + it * IT + ty * 8 + u] = __float_as_uint(d);  // exclusive owner
        }
    }
}

__global__ __launch_bounds__(256) void cf_reduce1(const unsigned* __restrict__ minbuf,
                                                  float* __restrict__ partial) {
    __shared__ float sm[4];
    const int base = blockIdx.x * 1024;
    float s = 0.0f;
    for (int k = threadIdx.x; k < 1024; k += 256)
        s += __uint_as_float(minbuf[base + k]);
#pragma unroll
    for (int off = 32; off > 0; off >>= 1)
        s += __shfl_down(s, off, 64);
    if ((threadIdx.x & 63) == 0) sm[threadIdx.x >> 6] = s;
    __syncthreads();
    if (threadIdx.x == 0)
        partial[blockIdx.x] = sm[0] + sm[1] + sm[2] + sm[3];
}

__global__ __launch_bounds__(256) void cf_reduce2(const float* __restrict__ partial,
                                                  float* __restrict__ out) {
    __shared__ float sm[4];
    float s = partial[threadIdx.x];
#pragma unroll
    for (int off = 32; off > 0; off >>= 1)
        s += __shfl_down(s, off, 64);
    if ((threadIdx.x & 63) == 0) sm[threadIdx.x >> 6] = s;
    __syncthreads();
    if (threadIdx.x == 0)
        out[0] = (sm[0] + sm[1] + sm[2] + sm[3]) * (1.0f / 64.0f);
}

extern "C" void kernel_launch(void* const* d_in, const int* in_sizes, int n_in,
                              void* d_out, int out_size, void* d_ws, size_t ws_size,
                              hipStream_t stream) {
    const float* preds = (const float*)d_in[0];
    const float* gts   = (const float*)d_in[1];
    const int*   idx   = (const int*)d_in[2];
    float* out = (float*)d_out;

    unsigned* minbuf = (unsigned*)d_ws;                                   // 1 MiB
    float* partial   = (float*)((char*)d_ws + NMIN * sizeof(unsigned));   // 1 KiB

    cf_init<<<NMIN / 256, 256, 0, stream>>>(minbuf);
    cf_tile<<<NB * NIT, BLK, 0, stream>>>(preds, gts, idx, minbuf);
    cf_reduce1<<<NMIN / 1024, 256, 0, stream>>>(minbuf, partial);
    cf_reduce2<<<1, 256, 0, stream>>>(partial, out);
}